// Round 8
// baseline (170.508 us; speedup 1.0000x reference)
//
#include <hip/hip_runtime.h>
#include <hip/hip_bf16.h>

// Problem dims (fixed by reference)
#define B_ROWS   8192
#define K_DIM    2048
#define OUT_COLS 4096
#define EPS      1e-5f

// 256x256 tile, BK=64, 8 waves (2M x 4N), mfma 16x16x32.
// m201-style 8-phase / 2-K-tile iteration: 2 barriers per phase, explicit
// lgkmcnt(0) before MFMA, counted vmcnt(4) twice per iteration, B-frag reads
// rebalanced 4+4 with register ping-pong (bbA/bbB).
#define BM 256
#define BN 256
#define BK 64
#define NT (K_DIM / BK)   // 32 K-tiles

using f32x4  = __attribute__((ext_vector_type(4))) float;
using bf16x8 = __attribute__((ext_vector_type(8))) short;   // 8 bf16 = 4 VGPRs

__device__ __forceinline__ unsigned short f2bf_rn(float f) {
    unsigned u = __builtin_bit_cast(unsigned, f);
    u += 0x7FFFu + ((u >> 16) & 1u);   // RNE (inputs finite)
    return (unsigned short)(u >> 16);
}

__global__ void cvt_all(const float* __restrict__ x, const float* __restrict__ w,
                        unsigned short* __restrict__ xb, unsigned short* __restrict__ wb) {
    const int n4x = (B_ROWS * K_DIM) / 4;
    const int n4w = (OUT_COLS * K_DIM) / 4;
    int stride = gridDim.x * blockDim.x;
    for (int i = blockIdx.x * blockDim.x + threadIdx.x; i < n4x + n4w; i += stride) {
        const float4* src; ushort4* dst; int j;
        if (i < n4x) { src = (const float4*)x; dst = (ushort4*)xb; j = i; }
        else         { src = (const float4*)w; dst = (ushort4*)wb; j = i - n4x; }
        float4 v = src[j];
        ushort4 r;
        r.x = f2bf_rn(v.x); r.y = f2bf_rn(v.y); r.z = f2bf_rn(v.z); r.w = f2bf_rn(v.w);
        dst[j] = r;
    }
}

__device__ __forceinline__ void gload16(const unsigned short* src, unsigned short* lds) {
    __builtin_amdgcn_global_load_lds((const __attribute__((address_space(1))) void*)src,
                                     (__attribute__((address_space(3))) void*)lds,
                                     16, 0, 0);
}

// 16-lane row sum via DPP row_ror (pure VALU): all 16 lanes get the total
__device__ __forceinline__ float rowsum16(float v) {
    int x;
    x = __builtin_amdgcn_update_dpp(0, __builtin_bit_cast(int, v), 0x121, 0xF, 0xF, true);
    v += __builtin_bit_cast(float, x);
    x = __builtin_amdgcn_update_dpp(0, __builtin_bit_cast(int, v), 0x122, 0xF, 0xF, true);
    v += __builtin_bit_cast(float, x);
    x = __builtin_amdgcn_update_dpp(0, __builtin_bit_cast(int, v), 0x124, 0xF, 0xF, true);
    v += __builtin_bit_cast(float, x);
    x = __builtin_amdgcn_update_dpp(0, __builtin_bit_cast(int, v), 0x128, 0xF, 0xF, true);
    v += __builtin_bit_cast(float, x);
    return v;
}

// stage one half-tile (128 rows x 64 k): linear LDS dest, per-row XOR-permuted global src
#define STA(BUF, H, KT) do {                                                        \
    gload16(Ag + (H)*262144 + (KT)*64 + goff0, &As[BUF][(H)*8192 + lds0]);          \
    gload16(Ag + (H)*262144 + (KT)*64 + goff1, &As[BUF][(H)*8192 + lds1]);          \
  } while (0)
#define STB(BUF, H, KT) do {                                                        \
    gload16(Bg + (H)*262144 + (KT)*64 + goff0, &Bs[BUF][(H)*8192 + lds0]);          \
    gload16(Bg + (H)*262144 + (KT)*64 + goff1, &Bs[BUF][(H)*8192 + lds1]);          \
  } while (0)

// one kk-half of the B fragments (4 x ds_read_b128) into named ping-pong buffer
#define RD_BH(DST, CURB, KK) do {                                                   \
    _Pragma("unroll") for (int n = 0; n < 4; ++n) {                                 \
      const int ro = browb + n * 16 * BK;                                           \
      DST[n][KK] = *(const bf16x8*)&(CURB)[ro + ((KK) ? colsw1 : colsw0)];          \
    } } while (0)

// one A-quadrant (2 m-frags x 2 kk) consumed THIS phase (4 x ds_read_b128)
#define RD_A(CURA, Q) do {                                                          \
    _Pragma("unroll") for (int dm = 0; dm < 2; ++dm) {                              \
      const int ro = arow + (2*(Q)+dm) * 16 * BK;                                   \
      af[dm][0] = *(const bf16x8*)&(CURA)[ro + colsw0];                             \
      af[dm][1] = *(const bf16x8*)&(CURA)[ro + colsw1];                             \
    } } while (0)

#define MFMAQ(BB, Q) do {                                                           \
    _Pragma("unroll") for (int kk = 0; kk < 2; ++kk)                                \
      _Pragma("unroll") for (int dm = 0; dm < 2; ++dm)                              \
        _Pragma("unroll") for (int n = 0; n < 4; ++n)                               \
          acc[2*(Q)+dm][n] = __builtin_amdgcn_mfma_f32_16x16x32_bf16(               \
              af[dm][kk], BB[n][kk], acc[2*(Q)+dm][n], 0, 0, 0);                    \
  } while (0)

#define VW4  asm volatile("s_waitcnt vmcnt(4)" ::: "memory")
#define BAR  __builtin_amdgcn_s_barrier()

// 2-barrier phase: reads+stage -> barrier -> lgkm(0) -> prio MFMA -> [VW4] -> barrier
#define PH(PRERD, STAGE, MFMAS, TAILW) do {                                         \
    PRERD; STAGE;                                                                   \
    __builtin_amdgcn_s_barrier();                                                   \
    asm volatile("s_waitcnt lgkmcnt(0)" ::: "memory");                              \
    __builtin_amdgcn_sched_barrier(0);                                              \
    __builtin_amdgcn_s_setprio(1);                                                  \
    MFMAS;                                                                          \
    __builtin_amdgcn_s_setprio(0);                                                  \
    TAILW;                                                                          \
    __builtin_amdgcn_s_barrier();                                                   \
  } while (0)

#define NOP_ ((void)0)

__global__ __launch_bounds__(512, 2) void gemm_gn(const unsigned short* __restrict__ A,
                                                  const unsigned short* __restrict__ Bw,
                                                  const float* __restrict__ bias,
                                                  float* __restrict__ out) {
    __shared__ __align__(16) unsigned short As[2][16384];   // 2 x 32 KB
    __shared__ __align__(16) unsigned short Bs[2][16384];   // 2 x 32 KB
    __shared__ __align__(16) float redbuf[256 * 8];         // 8 KB GN scratch

    const int tid  = threadIdx.x;
    const int lane = tid & 63;
    const int wave = tid >> 6;        // 0..7
    const int wr   = wave >> 2;       // 0..1 (M)
    const int wcn  = wave & 3;        // 0..3 (N)
    const int l16  = lane & 15;
    const int lhi  = lane >> 4;

    // T1: XCD-aware bijective swizzle (512 % 8 == 0)
    const int bid  = blockIdx.x;
    const int swz  = (bid & 7) * (gridDim.x >> 3) + (bid >> 3);
    const int brow = swz >> 4;        // 0..31
    const int bcol = swz & 15;        // 0..15

    // staging offsets: slot f -> row f>>3, chunk (f&7)^(row&7)
    int goff0, goff1, lds0, lds1;
    {
        int f0 = tid;          int r0 = f0 >> 3;
        int f1 = 512 + tid;    int r1 = f1 >> 3;
        goff0 = r0 * K_DIM + (((f0 & 7) ^ (r0 & 7)) * 8);
        goff1 = r1 * K_DIM + (((f1 & 7) ^ (r1 & 7)) * 8);
        lds0  = f0 * 8;
        lds1  = f1 * 8;
    }
    const unsigned short* Ag = A  + (size_t)brow * BM * K_DIM;
    const unsigned short* Bg = Bw + (size_t)bcol * BN * K_DIM;

    // swizzled fragment-read column offsets (ushort units); row&7 == l16&7
    const int colsw0 = (0 * 32 + lhi * 8) ^ ((l16 & 7) << 3);
    const int colsw1 = (1 * 32 + lhi * 8) ^ ((l16 & 7) << 3);
    const int arow   = (wr * 128 + l16) * BK;
    const int browb  = (wcn * 64 + l16) * BK;

    const unsigned short* A0p = &As[0][0];
    const unsigned short* A1p = &As[1][0];
    const unsigned short* B0p = &Bs[0][0];
    const unsigned short* B1p = &Bs[1][0];

    // bias folded into accumulator init
    f32x4 acc[8][4];
    {
        float bv[4];
        #pragma unroll
        for (int n = 0; n < 4; ++n)
            bv[n] = bias[bcol * BN + wcn * 64 + n * 16 + l16];
        #pragma unroll
        for (int m = 0; m < 8; ++m)
            #pragma unroll
            for (int n = 0; n < 4; ++n)
                #pragma unroll
                for (int j = 0; j < 4; ++j)
                    acc[m][n][j] = bv[n];
    }

    bf16x8 af[2][2];
    bf16x8 bbA[4][2];   // B fragments, even tiles
    bf16x8 bbB[4][2];   // B fragments, odd tiles

    // ---- prologue: A(0)->As0, B(0)->Bs0, B(1)->Bs1; leave B(1)'s 4 in flight
    STA(0, 0, 0); STA(0, 1, 0);
    STB(0, 0, 0); STB(0, 1, 0);
    STB(1, 0, 1); STB(1, 1, 1);
    VW4;                       // A(0), B(0) landed (every wave), B(1) in flight
    BAR;
    RD_BH(bbA, B0p, 0); RD_BH(bbA, B0p, 1);   // drained by ph0's lgkm(0)

    // Steady-state VMEM queue never drains below 4 (one B-tile stays in flight).
    // VW4 placements give every drained load >=2 phases (~1500 cyc) of lead, and
    // every LDS read of a staged buffer happens only after a barrier that follows
    // ALL waves' vmcnt drain of it.
    #pragma unroll 1
    for (int tt = 0; tt < NT; tt += 2) {
        const int k1 = (tt + 1) & (NT - 1);
        const int k2 = (tt + 2) & (NT - 1);
        const int k3 = (tt + 3) & (NT - 1);
        // ---- tile tt (As[0], bbA) ----
        PH( RD_A(A0p, 0),                     STA(1,0,k1); STA(1,1,k1),  MFMAQ(bbA, 0), NOP_ );
        PH( RD_A(A0p, 1),                     STB(0,0,k2); STB(0,1,k2),  MFMAQ(bbA, 1), VW4  );
        PH( RD_A(A0p, 2); RD_BH(bbB, B1p, 0), NOP_,                      MFMAQ(bbA, 2), NOP_ );
        PH( RD_A(A0p, 3); RD_BH(bbB, B1p, 1), NOP_,                      MFMAQ(bbA, 3), NOP_ );
        // ---- tile tt+1 (As[1], bbB) ----
        PH( RD_A(A1p, 0),                     STA(0,0,k2); STA(0,1,k2),  MFMAQ(bbB, 0), NOP_ );
        PH( RD_A(A1p, 1),                     STB(1,0,k3); STB(1,1,k3),  MFMAQ(bbB, 1), VW4  );
        PH( RD_A(A1p, 2); RD_BH(bbA, B0p, 0), NOP_,                      MFMAQ(bbB, 2), NOP_ );
        PH( RD_A(A1p, 3); RD_BH(bbA, B0p, 1), NOP_,                      MFMAQ(bbB, 3), NOP_ );
    }

    // ---- epilogue: GroupNorm over 128-col groups (block-local), clip, store ----
    // pass 1: per-row (s, s2) over this wave's 64 cols; DPP reduce into redbuf.
    // C/D layout (16x16): col = lane&15, row = (lane>>4)*4 + j
    #pragma unroll
    for (int m = 0; m < 8; ++m) {
        #pragma unroll
        for (int j = 0; j < 4; ++j) {
            float s = 0.f, s2 = 0.f;
            #pragma unroll
            for (int n = 0; n < 4; ++n) {
                float v = acc[m][n][j];
                s += v; s2 += v * v;
            }
            s  = rowsum16(s);
            s2 = rowsum16(s2);
            if (l16 == 0) {
                int r = wr * 128 + m * 16 + lhi * 4 + j;
                redbuf[r * 8 + wcn * 2 + 0] = s;
                redbuf[r * 8 + wcn * 2 + 1] = s2;
            }
        }
    }
    // drain in-flight dummy stages (wrapped kt) before kernel end
    asm volatile("s_waitcnt vmcnt(0)" ::: "memory");
    __syncthreads();

    // pass 2: combine wave pair per 128-col group (float4 broadcast), normalize, clip, store
    const int p2 = (wcn & 2) * 2;
    #pragma unroll
    for (int m = 0; m < 8; ++m) {
        #pragma unroll
        for (int j = 0; j < 4; ++j) {
            const int r = wr * 128 + m * 16 + lhi * 4 + j;
            const float4 q = *(const float4*)&redbuf[r * 8 + p2];
            const float mean = (q.x + q.z) * (1.0f / 128.0f);
            const float var  = (q.y + q.w) * (1.0f / 128.0f) - mean * mean;
            const float rstd = rsqrtf(var + EPS);
            float* orow = out + (size_t)(brow * BM + r) * OUT_COLS + bcol * BN + wcn * 64 + l16;
            #pragma unroll
            for (int n = 0; n < 4; ++n) {
                float v = (acc[m][n][j] - mean) * rstd;
                v = fminf(fmaxf(v, -1.0f), 1.0f);
                orow[n * 16] = v;
            }
        }
    }
}

extern "C" void kernel_launch(void* const* d_in, const int* in_sizes, int n_in,
                              void* d_out, int out_size, void* d_ws, size_t ws_size,
                              hipStream_t stream) {
    const float* x    = (const float*)d_in[0];   // [8192][2048]
    const float* w    = (const float*)d_in[1];   // [4096][2048]
    const float* bias = (const float*)d_in[2];   // [4096]
    float* out        = (float*)d_out;           // [8192][4096]

    unsigned short* xb = (unsigned short*)d_ws;
    unsigned short* wb = xb + (size_t)B_ROWS * K_DIM;

    cvt_all<<<3072, 256, 0, stream>>>(x, w, xb, wb);

    dim3 grid((B_ROWS / BM) * (OUT_COLS / BN));   // 32 * 16 = 512
    gemm_gn<<<grid, 512, 0, stream>>>(xb, wb, bias, out);
}